// Round 4
// baseline (474.991 us; speedup 1.0000x reference)
//
#include <hip/hip_runtime.h>
#include <math.h>

#define DD 64
static constexpr float GAMMA_C = 0.1f;
static constexpr float EPS_C = 0.1f;

// ---------------------------------------------------------------------------
// Prep: transposed weight copies (so later resident-weight loads coalesce).
//   aWT[k*64+j]   = W[j][k] - W[k][j] - GAMMA*(j==k)   (= aW^T)
//   phiWT[k*64+j] = phiW[j][k]
// ---------------------------------------------------------------------------
__global__ __launch_bounds__(256) void k_prep(const float* __restrict__ W1,
                                              const float* __restrict__ phiW1,
                                              const float* __restrict__ W2,
                                              const float* __restrict__ phiW2,
                                              float* __restrict__ aWT1,
                                              float* __restrict__ phiWT1,
                                              float* __restrict__ aWT2,
                                              float* __restrict__ phiWT2) {
  int idx = blockIdx.x * 256 + threadIdx.x;
  if (idx >= 4096) return;
  int k = idx >> 6, j = idx & 63;
  float g = (j == k) ? GAMMA_C : 0.f;
  aWT1[idx] = W1[j * 64 + k] - W1[k * 64 + j] - g;
  aWT2[idx] = W2[j * 64 + k] - W2[k * 64 + j] - g;
  phiWT1[idx] = phiW1[j * 64 + k];
  phiWT2[idx] = phiW2[j * 64 + k];
}

// ---------------------------------------------------------------------------
// CSR build: in-degree histogram -> exclusive scan -> fill (by destination).
// ---------------------------------------------------------------------------
__global__ __launch_bounds__(256) void k_hist(const int* __restrict__ col,
                                              int* __restrict__ hist, int e) {
  int i = blockIdx.x * blockDim.x + threadIdx.x;
  int stride = gridDim.x * blockDim.x;
  for (; i < e; i += stride) atomicAdd(&hist[col[i]], 1);
}

__global__ __launch_bounds__(256) void k_scan1(const int* __restrict__ hist,
                                               int* __restrict__ rs,
                                               int* __restrict__ bsum, int n) {
  __shared__ int wtot[4];
  int b = blockIdx.x, t = threadIdx.x;
  int base = b * 2048 + t * 8;
  int v[8];
  int s = 0;
#pragma unroll
  for (int u = 0; u < 8; ++u) {
    int idx = base + u;
    v[u] = (idx < n) ? hist[idx] : 0;
    s += v[u];
  }
  int lane = t & 63, wid = t >> 6;
  int ws = s;
#pragma unroll
  for (int d = 1; d < 64; d <<= 1) {
    int o = __shfl_up(ws, d);
    if (lane >= d) ws += o;
  }
  if (lane == 63) wtot[wid] = ws;
  __syncthreads();
  int off = 0;
  for (int w = 0; w < wid; ++w) off += wtot[w];
  int run = ws - s + off;  // exclusive start of this thread's chunk (in-block)
#pragma unroll
  for (int u = 0; u < 8; ++u) {
    int idx = base + u;
    if (idx < n) rs[idx] = run;
    run += v[u];
  }
  if (t == 255) bsum[b] = run;  // block total
}

__global__ void k_scan2(const int* __restrict__ bsum, int* __restrict__ boff,
                        int nb, int* __restrict__ rs, int n, int e) {
  int t = threadIdx.x;  // single wave; nb <= 64
  int v = (t < nb) ? bsum[t] : 0;
  int s = v;
#pragma unroll
  for (int d = 1; d < 64; d <<= 1) {
    int o = __shfl_up(s, d);
    if (t >= d) s += o;
  }
  if (t < nb) boff[t] = s - v;
  if (t == 0) rs[n] = e;
}

__global__ __launch_bounds__(256) void k_scan3_dinv(int* __restrict__ rs,
                                                    const int* __restrict__ boff,
                                                    const int* __restrict__ hist,
                                                    float* __restrict__ dinv, int n) {
  int i = blockIdx.x * blockDim.x + threadIdx.x;
  if (i < n) {
    rs[i] += boff[i >> 11];
    dinv[i] = rsqrtf((float)(hist[i] + 1));  // +1 self-loop
  }
}

__global__ __launch_bounds__(256) void k_fill(const int* __restrict__ row,
                                              const int* __restrict__ col,
                                              const int* __restrict__ rs,
                                              int* __restrict__ fillc,
                                              const float* __restrict__ dinv,
                                              int2* __restrict__ csr, int e) {
  int i = blockIdx.x * blockDim.x + threadIdx.x;
  int stride = gridDim.x * blockDim.x;
  for (; i < e; i += stride) {
    int c = col[i];
    int r = row[i];
    int p = atomicAdd(&fillc[c], 1);
    csr[rs[c] + p] = make_int2(r, __float_as_int(dinv[r]));
  }
}

// ---------------------------------------------------------------------------
// xw = x @ phiW^T.  Wave-per-node (grid-stride), lane = output feature j.
// phiWT resident in 64 VGPRs (coalesced one-time load); x row via wave-
// uniform scalar loads; coalesced 256B row store. 4 partial accs for ILP.
// ---------------------------------------------------------------------------
__global__ __launch_bounds__(256) void k_xw(const float* __restrict__ x,
                                            const float* __restrict__ phiWT,
                                            float* __restrict__ xw, int n) {
  int lane = threadIdx.x & 63;
  int gw = __builtin_amdgcn_readfirstlane(
      (int)((blockIdx.x * blockDim.x + threadIdx.x) >> 6));
  int nw = (gridDim.x * blockDim.x) >> 6;
  float w[64];
#pragma unroll
  for (int k = 0; k < 64; ++k) w[k] = phiWT[k * 64 + lane];
  for (int i = gw; i < n; i += nw) {
    const float* xr = x + (size_t)i * DD;  // uniform address -> s_load
    float a0 = 0.f, a1 = 0.f, a2 = 0.f, a3 = 0.f;
#pragma unroll
    for (int k = 0; k < 64; k += 4) {
      a0 = fmaf(xr[k + 0], w[k + 0], a0);
      a1 = fmaf(xr[k + 1], w[k + 1], a1);
      a2 = fmaf(xr[k + 2], w[k + 2], a2);
      a3 = fmaf(xr[k + 3], w[k + 3], a3);
    }
    xw[(size_t)i * DD + lane] = (a0 + a1) + (a2 + a3);
  }
}

// ---------------------------------------------------------------------------
// Aggregation + antisym GEMV + combine, wave-per-node, lane = feature.
//   aggr = dinv[i] * ( dinv[i]*xw[i] + sum_edges dinv[r]*xw[r] )   [lane slice]
//   lin  = (x[i] @ aW^T)[lane] + b[lane]          (resident aWT, s_load x row)
//   val  = relu(x[i][lane] + EPS*tanh(lin + aggr))
//   FINAL: out[i] = dot(val, outW) + outb ; else x1 row store.
// ---------------------------------------------------------------------------
template <bool FINAL>
__global__ __launch_bounds__(256) void k_agg(const float* __restrict__ xin,
                                             const float* __restrict__ xw,
                                             const float* __restrict__ aWT,
                                             const float* __restrict__ b,
                                             const int2* __restrict__ csr,
                                             const int* __restrict__ rs,
                                             const float* __restrict__ dinv,
                                             const float* __restrict__ outW,
                                             const float* __restrict__ outb,
                                             float* __restrict__ xo,
                                             float* __restrict__ out, int n) {
  int lane = threadIdx.x & 63;
  int gw = __builtin_amdgcn_readfirstlane(
      (int)((blockIdx.x * blockDim.x + threadIdx.x) >> 6));
  int nw = (gridDim.x * blockDim.x) >> 6;
  float w[64];
#pragma unroll
  for (int k = 0; k < 64; ++k) w[k] = aWT[k * 64 + lane];
  float bj = b[lane];
  float ow = FINAL ? outW[lane] : 0.f;
  for (int i = gw; i < n; i += nw) {
    int s = rs[i];        // uniform -> s_load
    int t = rs[i + 1];
    float dvc = dinv[i];  // uniform
    size_t o = (size_t)i * DD + lane;
    float a0 = dvc * xw[o];  // self-loop term: dinv[i]*xw[i]
    float a1 = 0.f, a2 = 0.f, a3 = 0.f;
    int k = s;
    for (; k + 3 < t; k += 4) {  // csr[k] uniform -> s_load; 4 gathers in flight
      int2 e0 = csr[k], e1 = csr[k + 1], e2 = csr[k + 2], e3 = csr[k + 3];
      a0 = fmaf(xw[(size_t)e0.x * DD + lane], __int_as_float(e0.y), a0);
      a1 = fmaf(xw[(size_t)e1.x * DD + lane], __int_as_float(e1.y), a1);
      a2 = fmaf(xw[(size_t)e2.x * DD + lane], __int_as_float(e2.y), a2);
      a3 = fmaf(xw[(size_t)e3.x * DD + lane], __int_as_float(e3.y), a3);
    }
    for (; k < t; ++k) {
      int2 e0 = csr[k];
      a0 = fmaf(xw[(size_t)e0.x * DD + lane], __int_as_float(e0.y), a0);
    }
    float aggr = dvc * ((a0 + a1) + (a2 + a3));
    // antisymmetric GEMV: lane j accumulates sum_k x[i][k] * aW[j][k]
    const float* xr = xin + (size_t)i * DD;  // uniform -> s_load
    float l0 = 0.f, l1 = 0.f, l2 = 0.f, l3 = 0.f;
#pragma unroll
    for (int kk = 0; kk < 64; kk += 4) {
      l0 = fmaf(xr[kk + 0], w[kk + 0], l0);
      l1 = fmaf(xr[kk + 1], w[kk + 1], l1);
      l2 = fmaf(xr[kk + 2], w[kk + 2], l2);
      l3 = fmaf(xr[kk + 3], w[kk + 3], l3);
    }
    float tot = ((l0 + l1) + (l2 + l3)) + bj + aggr;
    float val = fmaxf(fmaf(EPS_C, tanhf(tot), xin[o]), 0.f);
    if (FINAL) {
      float p = val * ow;
#pragma unroll
      for (int sg = 32; sg > 0; sg >>= 1) p += __shfl_xor(p, sg);
      if (lane == 0) out[i] = p + outb[0];
    } else {
      xo[o] = val;
    }
  }
}

extern "C" void kernel_launch(void* const* d_in, const int* in_sizes, int n_in,
                              void* d_out, int out_size, void* d_ws, size_t ws_size,
                              hipStream_t stream) {
  const float* x     = (const float*)d_in[0];
  const float* W1    = (const float*)d_in[1];
  const float* phiW1 = (const float*)d_in[2];
  const float* b1    = (const float*)d_in[3];
  const float* W2    = (const float*)d_in[4];
  const float* phiW2 = (const float*)d_in[5];
  const float* b2    = (const float*)d_in[6];
  const float* outW  = (const float*)d_in[7];
  const float* outb  = (const float*)d_in[8];
  const int*   ei    = (const int*)d_in[9];

  int n = in_sizes[0] / DD;
  int e = in_sizes[9] / 2;
  const int* row = ei;
  const int* col = ei + e;
  float* out = (float*)d_out;

  // workspace carve (256B-aligned)
  char* w = (char*)d_ws;
  auto carve = [&](size_t bytes) {
    char* p = w;
    w += (bytes + 255) & ~(size_t)255;
    return p;
  };
  float* aWT1   = (float*)carve(4096 * 4);
  float* phiWT1 = (float*)carve(4096 * 4);
  float* aWT2   = (float*)carve(4096 * 4);
  float* phiWT2 = (float*)carve(4096 * 4);
  int*   hist   = (int*)carve((size_t)n * 4);   // hist+fillc adjacent:
  int*   fillc  = (int*)carve((size_t)n * 4);   //   one memset covers both
  int*   rs     = (int*)carve(((size_t)n + 1) * 4);
  int*   bsum   = (int*)carve(64 * 4);
  int*   boff   = (int*)carve(64 * 4);
  float* dinv   = (float*)carve((size_t)n * 4);
  int2*  csr    = (int2*)carve((size_t)e * 8);
  float* xw     = (float*)carve((size_t)n * DD * 4);
  float* x1     = (float*)carve((size_t)n * DD * 4);

  int nb_n   = (n + 255) / 256;
  int nb_e   = 2048;               // grid-stride blocks for edge kernels
  int nb_sc1 = (n + 2047) / 2048;  // scan blocks (49 for n=100k, <=64)
  int nb_xw  = 1024;               // 4096 waves, ~24 nodes each
  int nb_ag  = 2048;               // 8192 waves, ~12 nodes each

  size_t zbytes = (size_t)((char*)fillc - (char*)hist) + (size_t)n * 4;
  hipMemsetAsync(hist, 0, zbytes, stream);  // zeros hist and fillc

  // prep: transposed antisym/phi weights + CSR + dinv
  k_prep<<<16, 256, 0, stream>>>(W1, phiW1, W2, phiW2, aWT1, phiWT1, aWT2, phiWT2);
  k_hist<<<nb_e, 256, 0, stream>>>(col, hist, e);
  k_scan1<<<nb_sc1, 256, 0, stream>>>(hist, rs, bsum, n);
  k_scan2<<<1, 64, 0, stream>>>(bsum, boff, nb_sc1, rs, n, e);
  k_scan3_dinv<<<nb_n, 256, 0, stream>>>(rs, boff, hist, dinv, n);
  k_fill<<<nb_e, 256, 0, stream>>>(row, col, rs, fillc, dinv, csr, e);

  // layer 1
  k_xw<<<nb_xw, 256, 0, stream>>>(x, phiWT1, xw, n);
  k_agg<false><<<nb_ag, 256, 0, stream>>>(x, xw, aWT1, b1, csr, rs, dinv,
                                          nullptr, nullptr, x1, nullptr, n);

  // layer 2 (combine fused with output GEMV)
  k_xw<<<nb_xw, 256, 0, stream>>>(x1, phiWT2, xw, n);
  k_agg<true><<<nb_ag, 256, 0, stream>>>(x1, xw, aWT2, b2, csr, rs, dinv,
                                         outW, outb, nullptr, out, n);
}